// Round 15
// baseline (505.819 us; speedup 1.0000x reference)
//
#include <hip/hip_runtime.h>
#include <math.h>

#define LN_EPS 1e-5f

typedef __attribute__((ext_vector_type(8))) short bf16x8;
typedef __attribute__((ext_vector_type(4))) short bf16x4;
typedef __attribute__((ext_vector_type(4))) float f32x4;

#if __has_builtin(__builtin_amdgcn_mfma_f32_16x16x16bf16_1k)
#define REG_P 1
#define MFMA16(a, b, c) __builtin_amdgcn_mfma_f32_16x16x16bf16_1k(a, b, c, 0, 0, 0)
#else
#define REG_P 0
#endif

// async global->LDS, 16B per lane; LDS dest is wave-uniform base + lane*16
#define GLDS16(g, l) __builtin_amdgcn_global_load_lds( \
    (const __attribute__((address_space(1))) unsigned int*)(g), \
    (__attribute__((address_space(3))) unsigned int*)(l), 16, 0, 0)

__device__ __forceinline__ float b2f(unsigned short h) { return __uint_as_float(((unsigned)h) << 16); }
__device__ __forceinline__ unsigned short f2b(float f) {
  unsigned u = __float_as_uint(f);
  unsigned r = (u + 0x7fffu + ((u >> 16) & 1u)) >> 16;
  return (unsigned short)r;
}
__device__ __forceinline__ float ld(const float* p) { return *p; }
__device__ __forceinline__ float ld(const unsigned short* p) { return b2f(*p); }
__device__ __forceinline__ void st(float* p, float v) { *p = v; }
__device__ __forceinline__ void st(unsigned short* p, float v) { *p = f2b(v); }

// ---------- block reduction helper (256 threads, 4 waves) ----------
__device__ __forceinline__ float bred_sum(float v, float* red) {
  for (int o = 32; o; o >>= 1) v += __shfl_down(v, o, 64);
  int wid = threadIdx.x >> 6;
  __syncthreads();
  if ((threadIdx.x & 63) == 0) red[wid] = v;
  __syncthreads();
  return red[0] + red[1] + red[2] + red[3];
}

// ---------- unified prep: BN fold + weight bf16 casts + QK concat (q prescaled) ----------
__global__ void prep_all(
    const float* __restrict__ w1, const float* __restrict__ w2, const float* __restrict__ vw,
    const float* __restrict__ qw, const float* __restrict__ qb,
    const float* __restrict__ kw, const float* __restrict__ kb,
    const float* __restrict__ b1, const float* __restrict__ g1, const float* __restrict__ be1,
    const float* __restrict__ m1, const float* __restrict__ v1,
    const float* __restrict__ b2, const float* __restrict__ g2, const float* __restrict__ be2,
    const float* __restrict__ m2, const float* __restrict__ v2,
    unsigned short* __restrict__ w1b, unsigned short* __restrict__ w2b,
    unsigned short* __restrict__ vwb, unsigned short* __restrict__ qkw,
    float* __restrict__ qkbias, float* __restrict__ s1, float* __restrict__ f1,
    float* __restrict__ s2, float* __restrict__ f2)
{
  const float scl = 0.044194173824159216f * 1.4426950408889634f;  // 512^-0.5 * log2(e)
  int idx = blockIdx.x * 256 + threadIdx.x;
  {  // QK concat: [3][1024][512], cols 0-511 = q*scl, 512-1023 = k
    int j = idx >> 19; int r = idx & 524287; int n = r >> 9; int k = r & 511;
    float v = (n < 512) ? qw[j * 262144 + n * 512 + k] * scl
                        : kw[j * 262144 + (n - 512) * 512 + k];
    qkw[idx] = f2b(v);
  }
  if (idx < 524288) { w1b[idx] = f2b(w1[idx]); w2b[idx] = f2b(w2[idx]); }
  if (idx < 786432) vwb[idx] = f2b(vw[idx]);
  if (idx < 3072) {
    int j = idx >> 10, n = idx & 1023;
    qkbias[idx] = (n < 512) ? qb[j * 512 + n] * scl : kb[j * 512 + n - 512];
  }
  if (idx < 1024) { float s = g1[idx] * rsqrtf(v1[idx] + LN_EPS); s1[idx] = s; f1[idx] = (b1[idx] - m1[idx]) * s + be1[idx]; }
  if (idx < 512)  { float s = g2[idx] * rsqrtf(v2[idx] + LN_EPS); s2[idx] = s; f2[idx] = (b2[idx] - m2[idx]) * s + be2[idx]; }
}

// ---------- 32x32 tiled transpose, typed: src[R][Cc] -> dst[Cc][R] ----------
template<typename TS, typename TD>
__global__ __launch_bounds__(256) void transpose_t(const TS* __restrict__ src,
    TD* __restrict__ dst, int R, int Cc, long sS, long sD) {
  __shared__ float t[32][33];
  src += (long)blockIdx.z * sS; dst += (long)blockIdx.z * sD;
  int c0 = blockIdx.x * 32, r0 = blockIdx.y * 32;
  int tx = threadIdx.x & 31, ty = threadIdx.x >> 5;
#pragma unroll
  for (int rr = 0; rr < 32; rr += 8) t[ty + rr][tx] = ld(&src[(long)(r0 + ty + rr) * Cc + c0 + tx]);
  __syncthreads();
#pragma unroll
  for (int rr = 0; rr < 32; rr += 8) st(&dst[(long)(c0 + ty + rr) * R + r0 + tx], t[tx][ty + rr]);
}

// ---------- row softmax f32 -> bf16, row length PER*256 ----------
template<int PER>
__global__ __launch_bounds__(256) void softmax_k(const float* __restrict__ x,
    unsigned short* __restrict__ y, long bstr) {
  __shared__ float red[4];
  const int L = PER * 256;
  int b = blockIdx.y, r = blockIdx.x, tid = threadIdx.x;
  const float* p = x + (long)b * bstr + (long)r * L;
  unsigned short* o = y + (long)b * bstr + (long)r * L;
  float vals[PER];
  float mx = -1e30f;
#pragma unroll
  for (int t = 0; t < PER; t++) { float v = p[tid + (t << 8)]; vals[t] = v; mx = fmaxf(mx, v); }
  for (int ofs = 32; ofs; ofs >>= 1) mx = fmaxf(mx, __shfl_down(mx, ofs, 64));
  int wid = tid >> 6;
  if ((tid & 63) == 0) red[wid] = mx;
  __syncthreads();
  mx = fmaxf(fmaxf(red[0], red[1]), fmaxf(red[2], red[3]));
  float sm = 0.f;
#pragma unroll
  for (int t = 0; t < PER; t++) { float e = __expf(vals[t] - mx); vals[t] = e; sm += e; }
  sm = bred_sum(sm, red);
  float inv = 1.f / sm;
#pragma unroll
  for (int t = 0; t < PER; t++) o[tid + (t << 8)] = f2b(vals[t] * inv);
}

// ---------- GEMM arg bundle ----------
template<typename TC>
struct GArgs {
  const unsigned short* A; long sA; int lda;
  const unsigned short* B; long sB; int ldb;
  TC* C; long sC; int ldc;
  int M, N, K;
  const float* sc; const float* bi; float cscale; TC* ct;
};

// ---------- bf16 MFMA GEMM body ----------
// EPI: 0 none; 1 relu(v*sc[n]+bi[n]); 2 v*cscale; 3 v+bi[n]; 4 v+bi[m];
//      5 v*cscale + dual-write ct[n*M+m]; 6 EPI1 + dual-write ct[n*M+m]
template<int EPI, typename TC>
__device__ __forceinline__ void gemm_body(short* As, short* Bs,
    const unsigned short* __restrict__ A, int lda,
    const unsigned short* __restrict__ B, int ldb,
    TC* __restrict__ C, int ldc, int M, int K,
    const float* sc, const float* bi, float cscale, TC* ct,
    int bm, int bn)
{
  const int tid = threadIdx.x;
  const int lane = tid & 63, wid = tid >> 6;
  const int wm = wid >> 1, wn = wid & 1;
  const int l15 = lane & 15, l4 = lane >> 4, l7 = lane & 7;
  const int srow = lane >> 3;
  f32x4 acc[4][4] = {};
  for (int k0 = 0; k0 < K; k0 += 64) {
#pragma unroll
    for (int i = 0; i < 4; i++) {
      int row = (wid * 4 + i) * 8 + srow;
      int gcol = (l7 ^ (row & 7)) * 8;
      GLDS16(A + (long)(bm + row) * lda + k0 + gcol, &As[(wid * 4 + i) * 512]);
      GLDS16(B + (long)(bn + row) * ldb + k0 + gcol, &Bs[(wid * 4 + i) * 512]);
    }
    __syncthreads();
#pragma unroll
    for (int ks = 0; ks < 2; ks++) {
      bf16x8 af[4], bfr[4];
#pragma unroll
      for (int t = 0; t < 4; t++) {
        int ra = wm * 64 + t * 16 + l15;
        int rb = wn * 64 + t * 16 + l15;
        int ch = (l4 + 4 * ks) ^ (l15 & 7);
        af[t]  = *(const bf16x8*)&As[ra * 64 + ch * 8];
        bfr[t] = *(const bf16x8*)&Bs[rb * 64 + ch * 8];
      }
#pragma unroll
      for (int i = 0; i < 4; i++)
#pragma unroll
        for (int j2 = 0; j2 < 4; j2++)
          acc[i][j2] = __builtin_amdgcn_mfma_f32_16x16x32_bf16(af[i], bfr[j2], acc[i][j2], 0, 0, 0);
    }
    __syncthreads();
  }
#pragma unroll
  for (int i = 0; i < 4; i++) {
#pragma unroll
    for (int j2 = 0; j2 < 4; j2++) {
      int n = bn + wn * 64 + j2 * 16 + l15;
#pragma unroll
      for (int j = 0; j < 4; j++) {
        int m = bm + wm * 64 + i * 16 + l4 * 4 + j;
        float v = acc[i][j2][j];
        if (EPI == 1 || EPI == 6) v = fmaxf(fmaf(v, sc[n], bi[n]), 0.f);
        if (EPI == 2) v *= cscale;
        if (EPI == 3) v += bi[n];
        if (EPI == 4) v += bi[m];
        if (EPI == 5) v *= cscale;
        if (EPI == 5 || EPI == 6) st(&ct[(long)n * M + m], v);
        st(&C[(long)m * ldc + n], v);
      }
    }
  }
}

template<int EPI, typename TC>
__global__ __launch_bounds__(256) void gemm_bf16(GArgs<TC> g) {
  __shared__ short As[128 * 64];
  __shared__ short Bs[128 * 64];
  int b = blockIdx.z;
  gemm_body<EPI, TC>(As, Bs, g.A + (long)b * g.sA, g.lda, g.B + (long)b * g.sB, g.ldb,
      g.C + (long)b * g.sC, g.ldc, g.M, g.K, g.sc, g.bi, g.cscale,
      g.ct ? g.ct + (long)b * g.sC : (TC*)nullptr, blockIdx.y * 128, blockIdx.x * 128);
}

// pair dispatch: z 0-3 -> g0 (batch z), z 4-7 -> g1 (batch z-4); mb0/nb0 bound g0's grid
template<int EPI, typename TC>
__global__ __launch_bounds__(256) void gemm_pair(GArgs<TC> g0, GArgs<TC> g1, int mb0, int nb0) {
  __shared__ short As[128 * 64];
  __shared__ short Bs[128 * 64];
  int cfg = blockIdx.z >> 2, b = blockIdx.z & 3;
  if (!cfg && ((int)blockIdx.y >= mb0 || (int)blockIdx.x >= nb0)) return;
  const GArgs<TC>& g = cfg ? g1 : g0;
  gemm_body<EPI, TC>(As, Bs, g.A + (long)b * g.sA, g.lda, g.B + (long)b * g.sB, g.ldb,
      g.C + (long)b * g.sC, g.ldc, g.M, g.K, g.sc, g.bi, g.cscale,
      g.ct ? g.ct + (long)b * g.sC : (TC*)nullptr, blockIdx.y * 128, blockIdx.x * 128);
}

// ---------- flash attention body ----------
// 512 threads = 8 waves, 16 q-rows/wave -> 128 q-rows/block.
// qk: [B,S,1024] bf16 (q prescaled by 512^-0.5*log2e); vT: [B,512,S].
// REG_P: PV consumes P directly from registers via K=16 MFMA intrinsic (sacc's
// C/D layout == K=16 B-operand layout: q=l15, k=l4*4+j) -> no Ps LDS roundtrip.
// Fallback: round-13 Ps-LDS path. If pOut: write unnormalized f32 O + (m,l).
__device__ __forceinline__ void attn_body(short* Ks, short* Vs, short* Ps,
    const unsigned short* __restrict__ qk, const unsigned short* __restrict__ vT,
    unsigned short* __restrict__ out, float* __restrict__ pOut, float2* __restrict__ mlrow,
    int S, int qblk, int h, int b, int kt0, int ktN)
{
  const int tid = threadIdx.x, lane = tid & 63, wid = tid >> 6;
  const int l15 = lane & 15, l4 = lane >> 4, l7 = l15 & 7;
  const long qkb = (long)b * S * 1024;
  const long vbb = (long)b * 512 * S;
  const long obase = (long)b * S * 512;
  const int qr0 = qblk * 128 + wid * 16;
  const int kR0 = tid >> 4, kC0 = tid & 15;
  const int kR1 = (tid + 512) >> 4, kC1 = tid & 15;
  const int vR0 = tid >> 3, vC0 = tid & 7;
  const int vR1 = (tid + 512) >> 3, vC1 = tid & 7;
  bf16x8 qf[4];
#pragma unroll
  for (int ks = 0; ks < 4; ks++)
    qf[ks] = *(const bf16x8*)(qk + qkb + (long)(qr0 + l15) * 1024 + h * 128 + l4 * 8 + ks * 32);
  f32x4 O[8] = {};
  f32x4 Ol = {};
  float m_run = -1e30f;
#if REG_P
  bf16x4 ones4;
#pragma unroll
  for (int j = 0; j < 4; j++) ones4[j] = (short)0x3F80;   // bf16 1.0
#else
  bf16x8 onev;
#pragma unroll
  for (int j = 0; j < 8; j++) onev[j] = (short)0x3F80;
#endif
  int4 kr0, kr1, vr0, vr1;
  auto load_regs = [&](int kt) {
    kr0 = *(const int4*)(qk + qkb + (long)(kt * 64 + kR0) * 1024 + 512 + h * 128 + kC0 * 8);
    kr1 = *(const int4*)(qk + qkb + (long)(kt * 64 + kR1) * 1024 + 512 + h * 128 + kC1 * 8);
    vr0 = *(const int4*)(vT + vbb + (long)(h * 128 + vR0) * S + kt * 64 + vC0 * 8);
    vr1 = *(const int4*)(vT + vbb + (long)(h * 128 + vR1) * S + kt * 64 + vC1 * 8);
  };
  load_regs(kt0);
  for (int kt = kt0; kt < ktN; kt++) {
    __syncthreads();
    *(int4*)&Ks[kR0 * 128 + ((kC0 ^ (kR0 & 7)) << 3)] = kr0;
    *(int4*)&Ks[kR1 * 128 + ((kC1 ^ (kR1 & 7)) << 3)] = kr1;
    *(int4*)&Vs[vR0 * 64 + ((vC0 ^ (vR0 & 7)) << 3)] = vr0;
    *(int4*)&Vs[vR1 * 64 + ((vC1 ^ (vR1 & 7)) << 3)] = vr1;
    __syncthreads();
    if (kt + 1 < ktN) load_regs(kt + 1);
    f32x4 sacc[4] = {};
    __builtin_amdgcn_s_setprio(1);
#pragma unroll
    for (int f = 0; f < 4; f++) {
      int row = f * 16 + l15;
#pragma unroll
      for (int ks = 0; ks < 4; ks++) {
        bf16x8 kf = *(const bf16x8*)&Ks[row * 128 + (((l4 + 4 * ks) ^ l7) << 3)];
        sacc[f] = __builtin_amdgcn_mfma_f32_16x16x32_bf16(kf, qf[ks], sacc[f], 0, 0, 0);
      }
    }
    __builtin_amdgcn_s_setprio(0);
    float pmax = fmaxf(fmaxf(sacc[0][0], sacc[0][1]), sacc[0][2]);
    pmax = fmaxf(fmaxf(pmax, sacc[0][3]), sacc[1][0]);
    pmax = fmaxf(fmaxf(pmax, sacc[1][1]), sacc[1][2]);
    pmax = fmaxf(fmaxf(pmax, sacc[1][3]), sacc[2][0]);
    pmax = fmaxf(fmaxf(pmax, sacc[2][1]), sacc[2][2]);
    pmax = fmaxf(fmaxf(pmax, sacc[2][3]), sacc[3][0]);
    pmax = fmaxf(fmaxf(pmax, sacc[3][1]), sacc[3][2]);
    pmax = fmaxf(pmax, sacc[3][3]);
    pmax = fmaxf(pmax, __shfl_xor(pmax, 16, 64));
    pmax = fmaxf(pmax, __shfl_xor(pmax, 32, 64));
    if (!__all(pmax - m_run <= 8.f)) {
      float m_new = fmaxf(m_run, pmax);
      float corr = __builtin_exp2f(m_run - m_new);
      m_run = m_new;
      Ol[0] *= corr; Ol[1] *= corr; Ol[2] *= corr; Ol[3] *= corr;
#pragma unroll
      for (int fd = 0; fd < 8; fd++) {
        O[fd][0] *= corr; O[fd][1] *= corr; O[fd][2] *= corr; O[fd][3] *= corr;
      }
    }
#if REG_P
    // exp2 + pack P directly into K=16 B-operand fragments (k = l4*4 + j)
    bf16x4 pfr[4];
#pragma unroll
    for (int f = 0; f < 4; f++) {
      float e0 = __builtin_exp2f(sacc[f][0] - m_run);
      float e1 = __builtin_exp2f(sacc[f][1] - m_run);
      float e2 = __builtin_exp2f(sacc[f][2] - m_run);
      float e3 = __builtin_exp2f(sacc[f][3] - m_run);
      unsigned w0, w1;
      asm("v_cvt_pk_bf16_f32 %0, %1, %2" : "=v"(w0) : "v"(e0), "v"(e1));
      asm("v_cvt_pk_bf16_f32 %0, %1, %2" : "=v"(w1) : "v"(e2), "v"(e3));
      union { unsigned u[2]; bf16x4 v; } pk_;
      pk_.u[0] = w0; pk_.u[1] = w1;
      pfr[f] = pk_.v;
    }
    // PV: O[d][q] += V^T[d][kv-block f] * P[kv][q], K=16 per block; l via ones-MFMA
    __builtin_amdgcn_s_setprio(1);
#pragma unroll
    for (int f = 0; f < 4; f++) {
      Ol = MFMA16(ones4, pfr[f], Ol);
      int vofs = (((2 * f + (l4 >> 1)) ^ l7) << 3) + (l4 & 1) * 4;
#pragma unroll
      for (int fd = 0; fd < 8; fd++) {
        bf16x4 vf = *(const bf16x4*)&Vs[(fd * 16 + l15) * 64 + vofs];
        O[fd] = MFMA16(vf, pfr[f], O[fd]);
      }
    }
    __builtin_amdgcn_s_setprio(0);
#else
#pragma unroll
    for (int f = 0; f < 4; f++) {
      float e0 = __builtin_exp2f(sacc[f][0] - m_run);
      float e1 = __builtin_exp2f(sacc[f][1] - m_run);
      float e2 = __builtin_exp2f(sacc[f][2] - m_run);
      float e3 = __builtin_exp2f(sacc[f][3] - m_run);
      unsigned w0, w1;
      asm("v_cvt_pk_bf16_f32 %0, %1, %2" : "=v"(w0) : "v"(e0), "v"(e1));
      asm("v_cvt_pk_bf16_f32 %0, %1, %2" : "=v"(w1) : "v"(e2), "v"(e3));
      int2 pw; pw.x = (int)w0; pw.y = (int)w1;
      *(int2*)&Ps[wid * 1024 + l15 * 64 + (((2 * f + (l4 >> 1)) ^ l7) << 3) + (l4 & 1) * 4] = pw;
    }
    __builtin_amdgcn_s_setprio(1);
#pragma unroll
    for (int ks = 0; ks < 2; ks++) {
      int pch = ((l4 + 4 * ks) ^ l7) << 3;
      bf16x8 pf = *(const bf16x8*)&Ps[wid * 1024 + l15 * 64 + pch];
      Ol = __builtin_amdgcn_mfma_f32_16x16x32_bf16(onev, pf, Ol, 0, 0, 0);
#pragma unroll
      for (int fd = 0; fd < 8; fd++) {
        bf16x8 vf = *(const bf16x8*)&Vs[(fd * 16 + l15) * 64 + pch];
        O[fd] = __builtin_amdgcn_mfma_f32_16x16x32_bf16(vf, pf, O[fd], 0, 0, 0);
      }
    }
    __builtin_amdgcn_s_setprio(0);
#endif
  }
  if (pOut) {
    float* pp = pOut + obase + (long)(qr0 + l15) * 512 + h * 128;
#pragma unroll
    for (int fd = 0; fd < 8; fd++) *(f32x4*)&pp[fd * 16 + l4 * 4] = O[fd];
    if (l4 == 0) mlrow[qr0 + l15] = make_float2(m_run, Ol[0]);
  } else {
    float inv = 1.f / Ol[0];
    unsigned short* op = out + obase + (long)(qr0 + l15) * 512 + h * 128;
#pragma unroll
    for (int fd = 0; fd < 8; fd++) {
      float a0 = O[fd][0] * inv, a1 = O[fd][1] * inv;
      float a2 = O[fd][2] * inv, a3 = O[fd][3] * inv;
      unsigned wA, wB;
      asm("v_cvt_pk_bf16_f32 %0, %1, %2" : "=v"(wA) : "v"(a0), "v"(a1));
      asm("v_cvt_pk_bf16_f32 %0, %1, %2" : "=v"(wB) : "v"(a2), "v"(a3));
      int2 ov; ov.x = (int)wA; ov.y = (int)wB;
      *(int2*)&op[fd * 16 + l4 * 4] = ov;
    }
  }
}

// att2 split-KV: z 0-3 -> split0 batch z, z 4-7 -> split1 batch z-4
__global__ __launch_bounds__(512) void attn_flash_split(
    const unsigned short* __restrict__ qk, const unsigned short* __restrict__ vT,
    float* __restrict__ P0, float* __restrict__ P1, float2* __restrict__ ml, int S)
{
  __shared__ short Ks[64 * 128];
  __shared__ short Vs[128 * 64];
#if REG_P
  short* Ps = nullptr;
#else
  __shared__ short Ps_s[8 * 1024];
  short* Ps = Ps_s;
#endif
  int split = blockIdx.z >> 2, b = blockIdx.z & 3;
  int half = (S >> 6) >> 1;
  int kt0 = split * half, ktN = kt0 + half;
  float* P = split ? P1 : P0;
  float2* mlrow = ml + (((long)split * 4 + b) * 4 + blockIdx.y) * S;
  attn_body(Ks, Vs, Ps, qk, vT, nullptr, P, mlrow, S, blockIdx.x, blockIdx.y, b, kt0, ktN);
}

// pair: att0 normal (z 0-3), att1 split0 (z 4-7), att1 split1 (z 8-11)
__global__ __launch_bounds__(512) void attn_flash_pair(
    const unsigned short* __restrict__ qk0, const unsigned short* __restrict__ vT0,
    unsigned short* __restrict__ out0,
    const unsigned short* __restrict__ qk1, const unsigned short* __restrict__ vT1,
    float* __restrict__ P0, float* __restrict__ P1, float2* __restrict__ ml)
{
  __shared__ short Ks[64 * 128];
  __shared__ short Vs[128 * 64];
#if REG_P
  short* Ps = nullptr;
#else
  __shared__ short Ps_s[8 * 1024];
  short* Ps = Ps_s;
#endif
  int cfg = blockIdx.z >> 2, b = blockIdx.z & 3;
  if (cfg == 0) {
    if ((int)blockIdx.x >= 8) return;
    attn_body(Ks, Vs, Ps, qk0, vT0, out0, nullptr, nullptr, 1024, blockIdx.x, blockIdx.y, b, 0, 16);
  } else {
    int split = cfg - 1;
    float* P = split ? P1 : P0;
    float2* mlrow = ml + (((long)split * 4 + b) * 4 + blockIdx.y) * 2048;
    attn_body(Ks, Vs, Ps, qk1, vT1, nullptr, P, mlrow, 2048, blockIdx.x, blockIdx.y, b,
              split * 16, split * 16 + 16);
  }
}

// ---------- residual add + LayerNorm over E=512 ----------
template<typename TD>
__device__ __forceinline__ void add_ln_body(
    const unsigned short* ap, const unsigned short* rp,
    const float* g, const float* bt, TD* dp, float* red)
{
  int tid = threadIdx.x;
  float y0 = b2f(ap[tid]) + b2f(rp[tid]);
  float y1 = b2f(ap[tid + 256]) + b2f(rp[tid + 256]);
  float mu = bred_sum(y0 + y1, red) * (1.f / 512.f);
  float d0 = y0 - mu, d1 = y1 - mu;
  float var = bred_sum(d0 * d0 + d1 * d1, red) * (1.f / 512.f);
  float rsv = rsqrtf(var + LN_EPS);
  st(&dp[tid], d0 * rsv * g[tid] + bt[tid]);
  st(&dp[tid + 256], d1 * rsv * g[tid + 256] + bt[tid + 256]);
}

// combine 2 KV-splits + residual + LN
template<typename TD>
__device__ __forceinline__ void add_ln_comb_body(
    const float* __restrict__ p0, const float* __restrict__ p1,
    const float2* __restrict__ ml, int S, int b, int s,
    const unsigned short* rp, const float* g, const float* bt, TD* dp, float* red)
{
  int tid = threadIdx.x;
  long base = ((long)b * S + s) * 512;
  float y[2];
#pragma unroll
  for (int t = 0; t < 2; t++) {
    int col = tid + t * 256;
    int h = col >> 7;
    float2 a = ml[(((long)0 + b) * 4 + h) * S + s];        // split 0
    float2 c = ml[(((long)4 + b) * 4 + h) * S + s];        // split 1
    float M = fmaxf(a.x, c.x);
    float w0 = __builtin_exp2f(a.x - M), w1 = __builtin_exp2f(c.x - M);
    float inv = 1.f / (a.y * w0 + c.y * w1);
    y[t] = (p0[base + col] * w0 + p1[base + col] * w1) * inv + b2f(rp[col]);
  }
  float mu = bred_sum(y[0] + y[1], red) * (1.f / 512.f);
  float d0 = y[0] - mu, d1 = y[1] - mu;
  float var = bred_sum(d0 * d0 + d1 * d1, red) * (1.f / 512.f);
  float rsv = rsqrtf(var + LN_EPS);
  st(&dp[tid], d0 * rsv * g[tid] + bt[tid]);
  st(&dp[tid + 256], d1 * rsv * g[tid + 256] + bt[tid + 256]);
}

// cfg0: att0 bf16 path (S=1024); cfg1: att1 split-combine (S=2048)
__global__ __launch_bounds__(256) void add_ln_pair2(
    const unsigned short* __restrict__ att0, const unsigned short* __restrict__ res0,
    const float* __restrict__ g0, const float* __restrict__ bt0,
    unsigned short* __restrict__ dst0, long db0,
    const float* __restrict__ P0, const float* __restrict__ P1,
    const float2* __restrict__ ml, const unsigned short* __restrict__ res1,
    const float* __restrict__ g1, const float* __restrict__ bt1,
    unsigned short* __restrict__ dst1, long db1)
{
  __shared__ float red[4];
  int b = blockIdx.y, s = blockIdx.x, cfg = blockIdx.z;
  if (cfg == 0) {
    if (s >= 1024) return;
    add_ln_body<unsigned short>(att0 + ((long)b * 1024 + s) * 512, res0 + ((long)b * 1024 + s) * 512,
                                g0, bt0, dst0 + (long)b * db0 + (long)s * 512, red);
  } else {
    add_ln_comb_body<unsigned short>(P0, P1, ml, 2048, b, s,
                                     res1 + ((long)b * 2048 + s) * 512,
                                     g1, bt1, dst1 + (long)b * db1 + (long)s * 512, red);
  }
}

__global__ __launch_bounds__(256) void add_ln_comb(
    const float* __restrict__ P0, const float* __restrict__ P1,
    const float2* __restrict__ ml, const unsigned short* __restrict__ resid,
    const float* __restrict__ g, const float* __restrict__ bt,
    float* __restrict__ dst, long db, int S)
{
  __shared__ float red[4];
  int b = blockIdx.y, s = blockIdx.x;
  add_ln_comb_body<float>(P0, P1, ml, S, b, s, resid + ((long)b * S + s) * 512,
                          g, bt, dst + (long)b * db + (long)s * 512, red);
}

extern "C" void kernel_launch(void* const* d_in, const int* in_sizes, int n_in,
                              void* d_out, int out_size, void* d_ws, size_t ws_size,
                              hipStream_t stream) {
  (void)in_sizes; (void)n_in; (void)out_size; (void)ws_size;
  const float* img = (const float*)d_in[0];
  const float* pts = (const float*)d_in[1];
  const float* w1  = (const float*)d_in[2];
  const float* b1  = (const float*)d_in[3];
  const float* g1  = (const float*)d_in[4];
  const float* be1 = (const float*)d_in[5];
  const float* m1  = (const float*)d_in[6];
  const float* v1  = (const float*)d_in[7];
  const float* w2  = (const float*)d_in[8];
  const float* b2  = (const float*)d_in[9];
  const float* g2  = (const float*)d_in[10];
  const float* be2 = (const float*)d_in[11];
  const float* m2  = (const float*)d_in[12];
  const float* v2  = (const float*)d_in[13];
  const float* qw  = (const float*)d_in[14];
  const float* qb  = (const float*)d_in[15];
  const float* kw  = (const float*)d_in[16];
  const float* kb  = (const float*)d_in[17];
  const float* vw  = (const float*)d_in[18];
  const float* vb  = (const float*)d_in[19];
  const float* lng = (const float*)d_in[20];
  const float* lnb = (const float*)d_in[21];
  float* out = (float*)d_out;
  float* ws  = (float*)d_ws;
  typedef unsigned short u16;

  // ---- arena (f32-slot offsets), total ~157.8 MB ----
  u16*   xTu   = (u16*)ws;                       // [4][3072][512] bf16
  float* phi   = ws;                             // [4][2048][1024] f32
  u16*   y1u   = (u16*)(ws + 8388608);           // [4][3072][1024] bf16
  float* phiT  = ws + 8388608;                   // [4][1024][2048] f32
  u16*   featu = (u16*)(ws + 16777216);          // [4][3072][512] bf16
  u16*   featTu= (u16*)(ws + 19922944);          // [4][512][3072] bf16
  u16*   smI   = (u16*)(ws + 23068672);          // phi_i softmax  [4][2048][1024] bf16
  u16*   smPT  = (u16*)(ws + 27262976);          // phi_p^T softmax [4][1024][2048] bf16
  u16*   Xi    = (u16*)(ws + 31457280);          // [4][1024][512] bf16
  u16*   Xp    = (u16*)(ws + 32505856);          // [4][2048][512] bf16
  u16*   jointu= (u16*)(ws + 34603008);          // [4][3072][512] bf16
  u16*   w1b   = (u16*)(ws + 37748736);
  u16*   w2b   = (u16*)(ws + 38010880);
  u16*   qkwb  = (u16*)(ws + 38273024);          // [3][1024][512] bf16 (q||k, q prescaled)
  u16*   vwb   = (u16*)(ws + 39059456);
  float* s1f   = ws + 39452672;
  float* f1f   = s1f + 1024;
  float* s2f   = f1f + 1024;
  float* f2f   = s2f + 512;
  float* qkbf  = ws + 39455744;                  // [3][1024] f32 bias (q prescaled)
  // attention scratch — pair phase (A0/B0 + dead regions)
  u16*   qk0   = (u16*)ws;                       // [4][1024][1024] bf16
  u16*   qk1   = (u16*)(ws + 2097152);           // [4][2048][1024] bf16
  u16*   vT0   = (u16*)(ws + 6291456);           // [4][512][1024] bf16
  u16*   vT1   = (u16*)(ws + 7340032);           // [4][512][2048] bf16
  u16*   out0  = (u16*)(ws + 9437184);           // [4][1024][512] bf16
  float* P0a1  = ws + 10485760;                  // att1 partial O, [4][2048][512] f32
  float* P1a1  = ws + 14680064;
  float2* ml1  = (float2*)(ws + 18874368);       // [2][4][4][2048] float2
  // att2 phase
  u16*   qkbu  = (u16*)ws;                       // [4][3072][1024] bf16
  u16*   vTu   = (u16*)(ws + 6291456);           // [4][512][3072] bf16
  float* P0a2  = ws + 9437184;                   // [4][3072][512] f32
  float* P1a2  = ws + 15728640;
  float2* ml2  = (float2*)(ws + 22020096);       // [2][4][4][3072] float2

  dim3 blk(256);
  prep_all<<<dim3(6144), blk, 0, stream>>>(w1, w2, vw, qw, qb, kw, kb,
      b1, g1, be1, m1, v1, b2, g2, be2, m2, v2,
      w1b, w2b, vwb, qkwb, qkbf, s1f, f1f, s2f, f2f);

  // xT: [pos, 512] bf16 (points rows 0..2047, img rows 2048..3071)
  transpose_t<float, u16><<<dim3(64, 16, 4), blk, 0, stream>>>(pts, xTu, 512, 2048, 1048576L, 1572864L);
  transpose_t<float, u16><<<dim3(32, 16, 4), blk, 0, stream>>>(img, xTu + 1048576, 512, 1024, 524288L, 1572864L);

  // MLP1: y1[pos,1024] = relu(bn1(xT @ w1^T))
  gemm_bf16<1, u16><<<dim3(8, 24, 4), blk, 0, stream>>>(
      GArgs<u16>{xTu, 1572864L, 512, w1b, 0L, 512, y1u, 3145728L, 1024,
                 3072, 1024, 512, s1f, f1f, 0.f, nullptr});
  // MLP2: feat[pos,512] + dual-write featT[512,3072]
  gemm_bf16<6, u16><<<dim3(4, 24, 4), blk, 0, stream>>>(
      GArgs<u16>{y1u, 3145728L, 1024, w2b, 0L, 1024, featu, 1572864L, 512,
                 3072, 512, 1024, s2f, f2f, 0.f, featTu});
  // phi[p,i] f32 + phiT[i,p] f32 in one pass
  gemm_bf16<5, float><<<dim3(8, 16, 4), blk, 0, stream>>>(
      GArgs<float>{featu, 1572864L, 512, featu + 1048576, 1572864L, 512, phi, 2097152L, 1024,
                   2048, 1024, 512, nullptr, nullptr, 0.044194173824159216f, phiT});
  softmax_k<4><<<dim3(2048, 4), blk, 0, stream>>>(phi, smI, 2097152L);    // softmax over i
  softmax_k<8><<<dim3(1024, 4), blk, 0, stream>>>(phiT, smPT, 2097152L);  // softmax over p
  // Xi[i,c] & Xp[p,c] merged
  gemm_pair<0, u16><<<dim3(4, 16, 8), blk, 0, stream>>>(
      GArgs<u16>{smPT, 2097152L, 2048, featTu, 1572864L, 3072, Xi, 524288L, 512,
                 1024, 512, 2048, nullptr, nullptr, 0.f, nullptr},
      GArgs<u16>{smI, 2097152L, 1024, featTu + 2048, 1572864L, 3072, Xp, 1048576L, 512,
                 2048, 512, 1024, nullptr, nullptr, 0.f, nullptr}, 8, 4);
  // QK projections att0+att1 merged
  gemm_pair<3, u16><<<dim3(8, 16, 8), blk, 0, stream>>>(
      GArgs<u16>{Xi, 524288L, 512, qkwb, 0L, 512, qk0, 1048576L, 1024,
                 1024, 1024, 512, nullptr, qkbf, 0.f, nullptr},
      GArgs<u16>{Xp, 1048576L, 512, qkwb + 524288, 0L, 512, qk1, 2097152L, 1024,
                 2048, 1024, 512, nullptr, qkbf + 1024, 0.f, nullptr}, 8, 8);
  // V projections (transposed output) att0+att1 merged
  gemm_pair<4, u16><<<dim3(16, 4, 8), blk, 0, stream>>>(
      GArgs<u16>{vwb, 0L, 512, Xi, 524288L, 512, vT0, 524288L, 1024,
                 512, 1024, 512, nullptr, vb, 0.f, nullptr},
      GArgs<u16>{vwb + 262144, 0L, 512, Xp, 1048576L, 512, vT1, 1048576L, 2048,
                 512, 2048, 512, nullptr, vb + 512, 0.f, nullptr}, 4, 8);
  // attention att0 (full) + att1 (2-way KV split) merged
  attn_flash_pair<<<dim3(16, 4, 12), dim3(512), 0, stream>>>(
      qk0, vT0, out0, qk1, vT1, P0a1, P1a1, ml1);
  // add+LN: att0 -> joint rows 2048..3071; att1 combine -> joint rows 0..2047
  add_ln_pair2<<<dim3(2048, 4, 2), blk, 0, stream>>>(
      out0, Xi, lng, lnb, jointu + 1048576, 1572864L,
      P0a1, P1a1, ml1, Xp, lng + 512, lnb + 512, jointu, 1572864L);
  // ---- att2: S=3072 on joint, 2-way KV split ----
  gemm_bf16<3, u16><<<dim3(8, 24, 4), blk, 0, stream>>>(
      GArgs<u16>{jointu, 1572864L, 512, qkwb + 1048576, 0L, 512, qkbu, 3145728L, 1024,
                 3072, 1024, 512, nullptr, qkbf + 2048, 0.f, nullptr});
  gemm_bf16<4, u16><<<dim3(24, 4, 4), blk, 0, stream>>>(
      GArgs<u16>{vwb + 524288, 0L, 512, jointu, 1572864L, 512, vTu, 1572864L, 3072,
                 512, 3072, 512, nullptr, vb + 1024, 0.f, nullptr});
  attn_flash_split<<<dim3(24, 4, 8), dim3(512), 0, stream>>>(qkbu, vTu, P0a2, P1a2, ml2, 3072);
  add_ln_comb<<<dim3(3072, 4), blk, 0, stream>>>(P0a2, P1a2, ml2, jointu,
      lng + 1024, lnb + 1024, out, 1572864L, 3072);
}

// Round 17
// 452.419 us; speedup vs baseline: 1.1180x; 1.1180x over previous
//
#include <hip/hip_runtime.h>
#include <math.h>

#define LN_EPS 1e-5f

typedef __attribute__((ext_vector_type(8))) short bf16x8;
typedef __attribute__((ext_vector_type(4))) float f32x4;

// async global->LDS, 16B per lane; LDS dest is wave-uniform base + lane*16
#define GLDS16(g, l) __builtin_amdgcn_global_load_lds( \
    (const __attribute__((address_space(1))) unsigned int*)(g), \
    (__attribute__((address_space(3))) unsigned int*)(l), 16, 0, 0)

__device__ __forceinline__ float b2f(unsigned short h) { return __uint_as_float(((unsigned)h) << 16); }
__device__ __forceinline__ unsigned short f2b(float f) {
  unsigned u = __float_as_uint(f);
  unsigned r = (u + 0x7fffu + ((u >> 16) & 1u)) >> 16;
  return (unsigned short)r;
}
__device__ __forceinline__ float ld(const float* p) { return *p; }
__device__ __forceinline__ float ld(const unsigned short* p) { return b2f(*p); }
__device__ __forceinline__ void st(float* p, float v) { *p = v; }
__device__ __forceinline__ void st(unsigned short* p, float v) { *p = f2b(v); }

// ---------- block reduction helper (256 threads, 4 waves) ----------
__device__ __forceinline__ float bred_sum(float v, float* red) {
  for (int o = 32; o; o >>= 1) v += __shfl_down(v, o, 64);
  int wid = threadIdx.x >> 6;
  __syncthreads();
  if ((threadIdx.x & 63) == 0) red[wid] = v;
  __syncthreads();
  return red[0] + red[1] + red[2] + red[3];
}

// ---------- unified prep: BN fold + weight bf16 casts + QK concat (q prescaled) ----------
__global__ void prep_all(
    const float* __restrict__ w1, const float* __restrict__ w2, const float* __restrict__ vw,
    const float* __restrict__ qw, const float* __restrict__ qb,
    const float* __restrict__ kw, const float* __restrict__ kb,
    const float* __restrict__ b1, const float* __restrict__ g1, const float* __restrict__ be1,
    const float* __restrict__ m1, const float* __restrict__ v1,
    const float* __restrict__ b2, const float* __restrict__ g2, const float* __restrict__ be2,
    const float* __restrict__ m2, const float* __restrict__ v2,
    unsigned short* __restrict__ w1b, unsigned short* __restrict__ w2b,
    unsigned short* __restrict__ vwb, unsigned short* __restrict__ qkw,
    float* __restrict__ qkbias, float* __restrict__ s1, float* __restrict__ f1,
    float* __restrict__ s2, float* __restrict__ f2)
{
  const float scl = 0.044194173824159216f * 1.4426950408889634f;  // 512^-0.5 * log2(e)
  int idx = blockIdx.x * 256 + threadIdx.x;
  {  // QK concat: [3][1024][512], cols 0-511 = q*scl, 512-1023 = k
    int j = idx >> 19; int r = idx & 524287; int n = r >> 9; int k = r & 511;
    float v = (n < 512) ? qw[j * 262144 + n * 512 + k] * scl
                        : kw[j * 262144 + (n - 512) * 512 + k];
    qkw[idx] = f2b(v);
  }
  if (idx < 524288) { w1b[idx] = f2b(w1[idx]); w2b[idx] = f2b(w2[idx]); }
  if (idx < 786432) vwb[idx] = f2b(vw[idx]);
  if (idx < 3072) {
    int j = idx >> 10, n = idx & 1023;
    qkbias[idx] = (n < 512) ? qb[j * 512 + n] * scl : kb[j * 512 + n - 512];
  }
  if (idx < 1024) { float s = g1[idx] * rsqrtf(v1[idx] + LN_EPS); s1[idx] = s; f1[idx] = (b1[idx] - m1[idx]) * s + be1[idx]; }
  if (idx < 512)  { float s = g2[idx] * rsqrtf(v2[idx] + LN_EPS); s2[idx] = s; f2[idx] = (b2[idx] - m2[idx]) * s + be2[idx]; }
}

// ---------- 32x32 tiled transpose, typed: src[R][Cc] -> dst[Cc][R] ----------
template<typename TS, typename TD>
__global__ __launch_bounds__(256) void transpose_t(const TS* __restrict__ src,
    TD* __restrict__ dst, int R, int Cc, long sS, long sD) {
  __shared__ float t[32][33];
  src += (long)blockIdx.z * sS; dst += (long)blockIdx.z * sD;
  int c0 = blockIdx.x * 32, r0 = blockIdx.y * 32;
  int tx = threadIdx.x & 31, ty = threadIdx.x >> 5;
#pragma unroll
  for (int rr = 0; rr < 32; rr += 8) t[ty + rr][tx] = ld(&src[(long)(r0 + ty + rr) * Cc + c0 + tx]);
  __syncthreads();
#pragma unroll
  for (int rr = 0; rr < 32; rr += 8) st(&dst[(long)(c0 + ty + rr) * R + r0 + tx], t[tx][ty + rr]);
}

// ---------- row softmax f32 -> bf16, row length PER*256 ----------
template<int PER>
__global__ __launch_bounds__(256) void softmax_k(const float* __restrict__ x,
    unsigned short* __restrict__ y, long bstr) {
  __shared__ float red[4];
  const int L = PER * 256;
  int b = blockIdx.y, r = blockIdx.x, tid = threadIdx.x;
  const float* p = x + (long)b * bstr + (long)r * L;
  unsigned short* o = y + (long)b * bstr + (long)r * L;
  float vals[PER];
  float mx = -1e30f;
#pragma unroll
  for (int t = 0; t < PER; t++) { float v = p[tid + (t << 8)]; vals[t] = v; mx = fmaxf(mx, v); }
  for (int ofs = 32; ofs; ofs >>= 1) mx = fmaxf(mx, __shfl_down(mx, ofs, 64));
  int wid = tid >> 6;
  if ((tid & 63) == 0) red[wid] = mx;
  __syncthreads();
  mx = fmaxf(fmaxf(red[0], red[1]), fmaxf(red[2], red[3]));
  float sm = 0.f;
#pragma unroll
  for (int t = 0; t < PER; t++) { float e = __expf(vals[t] - mx); vals[t] = e; sm += e; }
  sm = bred_sum(sm, red);
  float inv = 1.f / sm;
#pragma unroll
  for (int t = 0; t < PER; t++) o[tid + (t << 8)] = f2b(vals[t] * inv);
}

// ---------- GEMM arg bundle ----------
template<typename TC>
struct GArgs {
  const unsigned short* A; long sA; int lda;
  const unsigned short* B; long sB; int ldb;
  TC* C; long sC; int ldc;
  int M, N, K;
  const float* sc; const float* bi; float cscale; TC* ct;
};

// ---------- bf16 MFMA GEMM body ----------
// EPI: 0 none; 1 relu(v*sc[n]+bi[n]); 2 v*cscale; 3 v+bi[n]; 4 v+bi[m];
//      5 v*cscale + dual-write ct[n*M+m]; 6 EPI1 + dual-write ct[n*M+m]
template<int EPI, typename TC>
__device__ __forceinline__ void gemm_body(short* As, short* Bs,
    const unsigned short* __restrict__ A, int lda,
    const unsigned short* __restrict__ B, int ldb,
    TC* __restrict__ C, int ldc, int M, int K,
    const float* sc, const float* bi, float cscale, TC* ct,
    int bm, int bn)
{
  const int tid = threadIdx.x;
  const int lane = tid & 63, wid = tid >> 6;
  const int wm = wid >> 1, wn = wid & 1;
  const int l15 = lane & 15, l4 = lane >> 4, l7 = lane & 7;
  const int srow = lane >> 3;
  f32x4 acc[4][4] = {};
  for (int k0 = 0; k0 < K; k0 += 64) {
#pragma unroll
    for (int i = 0; i < 4; i++) {
      int row = (wid * 4 + i) * 8 + srow;
      int gcol = (l7 ^ (row & 7)) * 8;
      GLDS16(A + (long)(bm + row) * lda + k0 + gcol, &As[(wid * 4 + i) * 512]);
      GLDS16(B + (long)(bn + row) * ldb + k0 + gcol, &Bs[(wid * 4 + i) * 512]);
    }
    __syncthreads();
#pragma unroll
    for (int ks = 0; ks < 2; ks++) {
      bf16x8 af[4], bfr[4];
#pragma unroll
      for (int t = 0; t < 4; t++) {
        int ra = wm * 64 + t * 16 + l15;
        int rb = wn * 64 + t * 16 + l15;
        int ch = (l4 + 4 * ks) ^ (l15 & 7);
        af[t]  = *(const bf16x8*)&As[ra * 64 + ch * 8];
        bfr[t] = *(const bf16x8*)&Bs[rb * 64 + ch * 8];
      }
#pragma unroll
      for (int i = 0; i < 4; i++)
#pragma unroll
        for (int j2 = 0; j2 < 4; j2++)
          acc[i][j2] = __builtin_amdgcn_mfma_f32_16x16x32_bf16(af[i], bfr[j2], acc[i][j2], 0, 0, 0);
    }
    __syncthreads();
  }
#pragma unroll
  for (int i = 0; i < 4; i++) {
#pragma unroll
    for (int j2 = 0; j2 < 4; j2++) {
      int n = bn + wn * 64 + j2 * 16 + l15;
#pragma unroll
      for (int j = 0; j < 4; j++) {
        int m = bm + wm * 64 + i * 16 + l4 * 4 + j;
        float v = acc[i][j2][j];
        if (EPI == 1 || EPI == 6) v = fmaxf(fmaf(v, sc[n], bi[n]), 0.f);
        if (EPI == 2) v *= cscale;
        if (EPI == 3) v += bi[n];
        if (EPI == 4) v += bi[m];
        if (EPI == 5) v *= cscale;
        if (EPI == 5 || EPI == 6) st(&ct[(long)n * M + m], v);
        st(&C[(long)m * ldc + n], v);
      }
    }
  }
}

template<int EPI, typename TC>
__global__ __launch_bounds__(256) void gemm_bf16(GArgs<TC> g) {
  __shared__ short As[128 * 64];
  __shared__ short Bs[128 * 64];
  int b = blockIdx.z;
  gemm_body<EPI, TC>(As, Bs, g.A + (long)b * g.sA, g.lda, g.B + (long)b * g.sB, g.ldb,
      g.C + (long)b * g.sC, g.ldc, g.M, g.K, g.sc, g.bi, g.cscale,
      g.ct ? g.ct + (long)b * g.sC : (TC*)nullptr, blockIdx.y * 128, blockIdx.x * 128);
}

// pair dispatch: z 0-3 -> g0 (batch z), z 4-7 -> g1 (batch z-4); mb0/nb0 bound g0's grid
template<int EPI, typename TC>
__global__ __launch_bounds__(256) void gemm_pair(GArgs<TC> g0, GArgs<TC> g1, int mb0, int nb0) {
  __shared__ short As[128 * 64];
  __shared__ short Bs[128 * 64];
  int cfg = blockIdx.z >> 2, b = blockIdx.z & 3;
  if (!cfg && ((int)blockIdx.y >= mb0 || (int)blockIdx.x >= nb0)) return;
  const GArgs<TC>& g = cfg ? g1 : g0;
  gemm_body<EPI, TC>(As, Bs, g.A + (long)b * g.sA, g.lda, g.B + (long)b * g.sB, g.ldb,
      g.C + (long)b * g.sC, g.ldc, g.M, g.K, g.sc, g.bi, g.cscale,
      g.ct ? g.ct + (long)b * g.sC : (TC*)nullptr, blockIdx.y * 128, blockIdx.x * 128);
}

// ---------- flash attention body (round-13 structure; partials stored bf16) ----------
// 512 threads = 8 waves, 16 q-rows/wave -> 128 q-rows/block; 48 KB LDS.
// qk: [B,S,1024] bf16 (q prescaled by 512^-0.5*log2e); vT: [B,512,S].
// If pOut != nullptr: process KV tiles [kt0,ktN), write UNNORMALIZED bf16 O to pOut
// and per-q-row (m,l) f32 to mlrow[qr]; else write normalized bf16 to out.
__device__ __forceinline__ void attn_body(short* Ks, short* Vs, short* Ps,
    const unsigned short* __restrict__ qk, const unsigned short* __restrict__ vT,
    unsigned short* __restrict__ out, unsigned short* __restrict__ pOut,
    float2* __restrict__ mlrow,
    int S, int qblk, int h, int b, int kt0, int ktN)
{
  const int tid = threadIdx.x, lane = tid & 63, wid = tid >> 6;
  const int l15 = lane & 15, l4 = lane >> 4, l7 = l15 & 7;
  const long qkb = (long)b * S * 1024;
  const long vbb = (long)b * 512 * S;
  const long obase = (long)b * S * 512;
  const int qr0 = qblk * 128 + wid * 16;
  const int kR0 = tid >> 4, kC0 = tid & 15;
  const int kR1 = (tid + 512) >> 4, kC1 = tid & 15;
  const int vR0 = tid >> 3, vC0 = tid & 7;
  const int vR1 = (tid + 512) >> 3, vC1 = tid & 7;
  bf16x8 qf[4];
#pragma unroll
  for (int ks = 0; ks < 4; ks++)
    qf[ks] = *(const bf16x8*)(qk + qkb + (long)(qr0 + l15) * 1024 + h * 128 + l4 * 8 + ks * 32);
  bf16x8 onev;
#pragma unroll
  for (int j = 0; j < 8; j++) onev[j] = (short)0x3F80;   // bf16 1.0
  f32x4 O[8] = {};
  f32x4 Ol = {};
  float m_run = -1e30f;
  int4 kr0, kr1, vr0, vr1;
  auto load_regs = [&](int kt) {
    kr0 = *(const int4*)(qk + qkb + (long)(kt * 64 + kR0) * 1024 + 512 + h * 128 + kC0 * 8);
    kr1 = *(const int4*)(qk + qkb + (long)(kt * 64 + kR1) * 1024 + 512 + h * 128 + kC1 * 8);
    vr0 = *(const int4*)(vT + vbb + (long)(h * 128 + vR0) * S + kt * 64 + vC0 * 8);
    vr1 = *(const int4*)(vT + vbb + (long)(h * 128 + vR1) * S + kt * 64 + vC1 * 8);
  };
  load_regs(kt0);
  for (int kt = kt0; kt < ktN; kt++) {
    __syncthreads();
    *(int4*)&Ks[kR0 * 128 + ((kC0 ^ (kR0 & 7)) << 3)] = kr0;
    *(int4*)&Ks[kR1 * 128 + ((kC1 ^ (kR1 & 7)) << 3)] = kr1;
    *(int4*)&Vs[vR0 * 64 + ((vC0 ^ (vR0 & 7)) << 3)] = vr0;
    *(int4*)&Vs[vR1 * 64 + ((vC1 ^ (vR1 & 7)) << 3)] = vr1;
    __syncthreads();
    if (kt + 1 < ktN) load_regs(kt + 1);
    f32x4 sacc[4] = {};
    __builtin_amdgcn_s_setprio(1);
#pragma unroll
    for (int f = 0; f < 4; f++) {
      int row = f * 16 + l15;
#pragma unroll
      for (int ks = 0; ks < 4; ks++) {
        bf16x8 kf = *(const bf16x8*)&Ks[row * 128 + (((l4 + 4 * ks) ^ l7) << 3)];
        sacc[f] = __builtin_amdgcn_mfma_f32_16x16x32_bf16(kf, qf[ks], sacc[f], 0, 0, 0);
      }
    }
    __builtin_amdgcn_s_setprio(0);
    float pmax = fmaxf(fmaxf(sacc[0][0], sacc[0][1]), sacc[0][2]);
    pmax = fmaxf(fmaxf(pmax, sacc[0][3]), sacc[1][0]);
    pmax = fmaxf(fmaxf(pmax, sacc[1][1]), sacc[1][2]);
    pmax = fmaxf(fmaxf(pmax, sacc[1][3]), sacc[2][0]);
    pmax = fmaxf(fmaxf(pmax, sacc[2][1]), sacc[2][2]);
    pmax = fmaxf(fmaxf(pmax, sacc[2][3]), sacc[3][0]);
    pmax = fmaxf(fmaxf(pmax, sacc[3][1]), sacc[3][2]);
    pmax = fmaxf(pmax, sacc[3][3]);
    pmax = fmaxf(pmax, __shfl_xor(pmax, 16, 64));
    pmax = fmaxf(pmax, __shfl_xor(pmax, 32, 64));
    if (!__all(pmax - m_run <= 8.f)) {
      float m_new = fmaxf(m_run, pmax);
      float corr = __builtin_exp2f(m_run - m_new);
      m_run = m_new;
      Ol[0] *= corr; Ol[1] *= corr; Ol[2] *= corr; Ol[3] *= corr;
#pragma unroll
      for (int fd = 0; fd < 8; fd++) {
        O[fd][0] *= corr; O[fd][1] *= corr; O[fd][2] *= corr; O[fd][3] *= corr;
      }
    }
#pragma unroll
    for (int f = 0; f < 4; f++) {
      float e0 = __builtin_exp2f(sacc[f][0] - m_run);
      float e1 = __builtin_exp2f(sacc[f][1] - m_run);
      float e2 = __builtin_exp2f(sacc[f][2] - m_run);
      float e3 = __builtin_exp2f(sacc[f][3] - m_run);
      unsigned w0, w1;
      asm("v_cvt_pk_bf16_f32 %0, %1, %2" : "=v"(w0) : "v"(e0), "v"(e1));
      asm("v_cvt_pk_bf16_f32 %0, %1, %2" : "=v"(w1) : "v"(e2), "v"(e3));
      int2 pw; pw.x = (int)w0; pw.y = (int)w1;
      *(int2*)&Ps[wid * 1024 + l15 * 64 + (((2 * f + (l4 >> 1)) ^ l7) << 3) + (l4 & 1) * 4] = pw;
    }
    __builtin_amdgcn_s_setprio(1);
#pragma unroll
    for (int ks = 0; ks < 2; ks++) {
      int pch = ((l4 + 4 * ks) ^ l7) << 3;
      bf16x8 pf = *(const bf16x8*)&Ps[wid * 1024 + l15 * 64 + pch];
      Ol = __builtin_amdgcn_mfma_f32_16x16x32_bf16(onev, pf, Ol, 0, 0, 0);
#pragma unroll
      for (int fd = 0; fd < 8; fd++) {
        bf16x8 vf = *(const bf16x8*)&Vs[(fd * 16 + l15) * 64 + pch];
        O[fd] = __builtin_amdgcn_mfma_f32_16x16x32_bf16(vf, pf, O[fd], 0, 0, 0);
      }
    }
    __builtin_amdgcn_s_setprio(0);
  }
  if (pOut) {
    unsigned short* pp = pOut + obase + (long)(qr0 + l15) * 512 + h * 128;
#pragma unroll
    for (int fd = 0; fd < 8; fd++) {
      unsigned wA, wB;
      float a0 = O[fd][0], a1 = O[fd][1], a2 = O[fd][2], a3 = O[fd][3];
      asm("v_cvt_pk_bf16_f32 %0, %1, %2" : "=v"(wA) : "v"(a0), "v"(a1));
      asm("v_cvt_pk_bf16_f32 %0, %1, %2" : "=v"(wB) : "v"(a2), "v"(a3));
      int2 ov; ov.x = (int)wA; ov.y = (int)wB;
      *(int2*)&pp[fd * 16 + l4 * 4] = ov;
    }
    if (l4 == 0) mlrow[qr0 + l15] = make_float2(m_run, Ol[0]);
  } else {
    float inv = 1.f / Ol[0];
    unsigned short* op = out + obase + (long)(qr0 + l15) * 512 + h * 128;
#pragma unroll
    for (int fd = 0; fd < 8; fd++) {
      float a0 = O[fd][0] * inv, a1 = O[fd][1] * inv;
      float a2 = O[fd][2] * inv, a3 = O[fd][3] * inv;
      unsigned wA, wB;
      asm("v_cvt_pk_bf16_f32 %0, %1, %2" : "=v"(wA) : "v"(a0), "v"(a1));
      asm("v_cvt_pk_bf16_f32 %0, %1, %2" : "=v"(wB) : "v"(a2), "v"(a3));
      int2 ov; ov.x = (int)wA; ov.y = (int)wB;
      *(int2*)&op[fd * 16 + l4 * 4] = ov;
    }
  }
}

// att2 split-KV: z 0-3 -> split0 batch z, z 4-7 -> split1 batch z-4
__global__ __launch_bounds__(512) void attn_flash_split(
    const unsigned short* __restrict__ qk, const unsigned short* __restrict__ vT,
    unsigned short* __restrict__ P0, unsigned short* __restrict__ P1,
    float2* __restrict__ ml, int S)
{
  __shared__ short Ks[64 * 128];
  __shared__ short Vs[128 * 64];
  __shared__ short Ps[8 * 1024];
  int split = blockIdx.z >> 2, b = blockIdx.z & 3;
  int half = (S >> 6) >> 1;
  int kt0 = split * half, ktN = kt0 + half;
  unsigned short* P = split ? P1 : P0;
  float2* mlrow = ml + (((long)split * 4 + b) * 4 + blockIdx.y) * S;
  attn_body(Ks, Vs, Ps, qk, vT, nullptr, P, mlrow, S, blockIdx.x, blockIdx.y, b, kt0, ktN);
}

// pair: att0 normal (z 0-3), att1 split0 (z 4-7), att1 split1 (z 8-11)
__global__ __launch_bounds__(512) void attn_flash_pair(
    const unsigned short* __restrict__ qk0, const unsigned short* __restrict__ vT0,
    unsigned short* __restrict__ out0,
    const unsigned short* __restrict__ qk1, const unsigned short* __restrict__ vT1,
    unsigned short* __restrict__ P0, unsigned short* __restrict__ P1,
    float2* __restrict__ ml)
{
  __shared__ short Ks[64 * 128];
  __shared__ short Vs[128 * 64];
  __shared__ short Ps[8 * 1024];
  int cfg = blockIdx.z >> 2, b = blockIdx.z & 3;
  if (cfg == 0) {
    if ((int)blockIdx.x >= 8) return;
    attn_body(Ks, Vs, Ps, qk0, vT0, out0, nullptr, nullptr, 1024, blockIdx.x, blockIdx.y, b, 0, 16);
  } else {
    int split = cfg - 1;
    unsigned short* P = split ? P1 : P0;
    float2* mlrow = ml + (((long)split * 4 + b) * 4 + blockIdx.y) * 2048;
    attn_body(Ks, Vs, Ps, qk1, vT1, nullptr, P, mlrow, 2048, blockIdx.x, blockIdx.y, b,
              split * 16, split * 16 + 16);
  }
}

// ---------- residual add + LayerNorm over E=512 ----------
template<typename TD>
__device__ __forceinline__ void add_ln_body(
    const unsigned short* ap, const unsigned short* rp,
    const float* g, const float* bt, TD* dp, float* red)
{
  int tid = threadIdx.x;
  float y0 = b2f(ap[tid]) + b2f(rp[tid]);
  float y1 = b2f(ap[tid + 256]) + b2f(rp[tid + 256]);
  float mu = bred_sum(y0 + y1, red) * (1.f / 512.f);
  float d0 = y0 - mu, d1 = y1 - mu;
  float var = bred_sum(d0 * d0 + d1 * d1, red) * (1.f / 512.f);
  float rsv = rsqrtf(var + LN_EPS);
  st(&dp[tid], d0 * rsv * g[tid] + bt[tid]);
  st(&dp[tid + 256], d1 * rsv * g[tid + 256] + bt[tid + 256]);
}

// combine 2 KV-splits (bf16 partials) + residual + LN
template<typename TD>
__device__ __forceinline__ void add_ln_comb_body(
    const unsigned short* __restrict__ p0, const unsigned short* __restrict__ p1,
    const float2* __restrict__ ml, int S, int b, int s,
    const unsigned short* rp, const float* g, const float* bt, TD* dp, float* red)
{
  int tid = threadIdx.x;
  long base = ((long)b * S + s) * 512;
  float y[2];
#pragma unroll
  for (int t = 0; t < 2; t++) {
    int col = tid + t * 256;
    int h = col >> 7;
    float2 a = ml[(((long)0 + b) * 4 + h) * S + s];        // split 0
    float2 c = ml[(((long)4 + b) * 4 + h) * S + s];        // split 1
    float M = fmaxf(a.x, c.x);
    float w0 = __builtin_exp2f(a.x - M), w1 = __builtin_exp2f(c.x - M);
    float inv = 1.f / (a.y * w0 + c.y * w1);
    y[t] = (b2f(p0[base + col]) * w0 + b2f(p1[base + col]) * w1) * inv + b2f(rp[col]);
  }
  float mu = bred_sum(y[0] + y[1], red) * (1.f / 512.f);
  float d0 = y[0] - mu, d1 = y[1] - mu;
  float var = bred_sum(d0 * d0 + d1 * d1, red) * (1.f / 512.f);
  float rsv = rsqrtf(var + LN_EPS);
  st(&dp[tid], d0 * rsv * g[tid] + bt[tid]);
  st(&dp[tid + 256], d1 * rsv * g[tid + 256] + bt[tid + 256]);
}

// cfg0: att0 bf16 path (S=1024); cfg1: att1 split-combine (S=2048)
__global__ __launch_bounds__(256) void add_ln_pair2(
    const unsigned short* __restrict__ att0, const unsigned short* __restrict__ res0,
    const float* __restrict__ g0, const float* __restrict__ bt0,
    unsigned short* __restrict__ dst0, long db0,
    const unsigned short* __restrict__ P0, const unsigned short* __restrict__ P1,
    const float2* __restrict__ ml, const unsigned short* __restrict__ res1,
    const float* __restrict__ g1, const float* __restrict__ bt1,
    unsigned short* __restrict__ dst1, long db1)
{
  __shared__ float red[4];
  int b = blockIdx.y, s = blockIdx.x, cfg = blockIdx.z;
  if (cfg == 0) {
    if (s >= 1024) return;
    add_ln_body<unsigned short>(att0 + ((long)b * 1024 + s) * 512, res0 + ((long)b * 1024 + s) * 512,
                                g0, bt0, dst0 + (long)b * db0 + (long)s * 512, red);
  } else {
    add_ln_comb_body<unsigned short>(P0, P1, ml, 2048, b, s,
                                     res1 + ((long)b * 2048 + s) * 512,
                                     g1, bt1, dst1 + (long)b * db1 + (long)s * 512, red);
  }
}

__global__ __launch_bounds__(256) void add_ln_comb(
    const unsigned short* __restrict__ P0, const unsigned short* __restrict__ P1,
    const float2* __restrict__ ml, const unsigned short* __restrict__ resid,
    const float* __restrict__ g, const float* __restrict__ bt,
    float* __restrict__ dst, long db, int S)
{
  __shared__ float red[4];
  int b = blockIdx.y, s = blockIdx.x;
  add_ln_comb_body<float>(P0, P1, ml, S, b, s, resid + ((long)b * S + s) * 512,
                          g, bt, dst + (long)b * db + (long)s * 512, red);
}

extern "C" void kernel_launch(void* const* d_in, const int* in_sizes, int n_in,
                              void* d_out, int out_size, void* d_ws, size_t ws_size,
                              hipStream_t stream) {
  (void)in_sizes; (void)n_in; (void)out_size; (void)ws_size;
  const float* img = (const float*)d_in[0];
  const float* pts = (const float*)d_in[1];
  const float* w1  = (const float*)d_in[2];
  const float* b1  = (const float*)d_in[3];
  const float* g1  = (const float*)d_in[4];
  const float* be1 = (const float*)d_in[5];
  const float* m1  = (const float*)d_in[6];
  const float* v1  = (const float*)d_in[7];
  const float* w2  = (const float*)d_in[8];
  const float* b2  = (const float*)d_in[9];
  const float* g2  = (const float*)d_in[10];
  const float* be2 = (const float*)d_in[11];
  const float* m2  = (const float*)d_in[12];
  const float* v2  = (const float*)d_in[13];
  const float* qw  = (const float*)d_in[14];
  const float* qb  = (const float*)d_in[15];
  const float* kw  = (const float*)d_in[16];
  const float* kb  = (const float*)d_in[17];
  const float* vw  = (const float*)d_in[18];
  const float* vb  = (const float*)d_in[19];
  const float* lng = (const float*)d_in[20];
  const float* lnb = (const float*)d_in[21];
  float* out = (float*)d_out;
  float* ws  = (float*)d_ws;
  typedef unsigned short u16;

  // ---- arena (f32-slot offsets), total ~157.8 MB ----
  u16*   xTu   = (u16*)ws;                       // [4][3072][512] bf16
  float* phi   = ws;                             // [4][2048][1024] f32
  u16*   y1u   = (u16*)(ws + 8388608);           // [4][3072][1024] bf16
  float* phiT  = ws + 8388608;                   // [4][1024][2048] f32
  u16*   featu = (u16*)(ws + 16777216);          // [4][3072][512] bf16
  u16*   featTu= (u16*)(ws + 19922944);          // [4][512][3072] bf16
  u16*   smI   = (u16*)(ws + 23068672);          // phi_i softmax  [4][2048][1024] bf16
  u16*   smPT  = (u16*)(ws + 27262976);          // phi_p^T softmax [4][1024][2048] bf16
  u16*   Xi    = (u16*)(ws + 31457280);          // [4][1024][512] bf16
  u16*   Xp    = (u16*)(ws + 32505856);          // [4][2048][512] bf16
  u16*   jointu= (u16*)(ws + 34603008);          // [4][3072][512] bf16
  u16*   w1b   = (u16*)(ws + 37748736);
  u16*   w2b   = (u16*)(ws + 38010880);
  u16*   qkwb  = (u16*)(ws + 38273024);          // [3][1024][512] bf16 (q||k, q prescaled)
  u16*   vwb   = (u16*)(ws + 39059456);
  float* s1f   = ws + 39452672;
  float* f1f   = s1f + 1024;
  float* s2f   = f1f + 1024;
  float* f2f   = s2f + 512;
  float* qkbf  = ws + 39455744;                  // [3][1024] f32 bias (q prescaled)
  // attention scratch — pair phase (A0/B0 + dead regions)
  // sizes in f32 slots: qk0 2,097,152 | qk1 4,194,304 | vT0 1,048,576 | vT1 2,097,152
  //                     out0 1,048,576 | P0a1/P1a1 2,097,152 each (bf16 [4][2048][512]... 
  //                     = 4,194,304 u16 = 2,097,152 slots) | ml1 131,072
  u16*   qk0   = (u16*)ws;                       // [0, 2097152)
  u16*   qk1   = (u16*)(ws + 2097152);           // [2097152, 6291456)
  u16*   vT0   = (u16*)(ws + 6291456);           // [6291456, 7340032)
  u16*   vT1   = (u16*)(ws + 7340032);           // [7340032, 9437184)
  u16*   out0  = (u16*)(ws + 9437184);           // [9437184, 10485760)
  u16*   P0a1  = (u16*)(ws + 10485760);          // [10485760, 12582912)  bf16 [4][2048][512]
  u16*   P1a1  = (u16*)(ws + 12582912);          // [12582912, 14680064)
  float2* ml1  = (float2*)(ws + 14680064);       // [14680064, 14811136)  [2][4][4][2048] float2
  // att2 phase (runs after pair phase completes; reuses same region)
  u16*   qkbu  = (u16*)ws;                       // [0, 6291456)
  u16*   vTu   = (u16*)(ws + 6291456);           // [6291456, 9437184)
  u16*   P0a2  = (u16*)(ws + 9437184);           // [9437184, 12582912)   bf16 [4][3072][512]
  u16*   P1a2  = (u16*)(ws + 12582912);          // [12582912, 15728640)
  float2* ml2  = (float2*)(ws + 15728640);       // [15728640, 15925248)  [2][4][4][3072] float2

  dim3 blk(256);
  prep_all<<<dim3(6144), blk, 0, stream>>>(w1, w2, vw, qw, qb, kw, kb,
      b1, g1, be1, m1, v1, b2, g2, be2, m2, v2,
      w1b, w2b, vwb, qkwb, qkbf, s1f, f1f, s2f, f2f);

  // xT: [pos, 512] bf16 (points rows 0..2047, img rows 2048..3071)
  transpose_t<float, u16><<<dim3(64, 16, 4), blk, 0, stream>>>(pts, xTu, 512, 2048, 1048576L, 1572864L);
  transpose_t<float, u16><<<dim3(32, 16, 4), blk, 0, stream>>>(img, xTu + 1048576, 512, 1024, 524288L, 1572864L);

  // MLP1: y1[pos,1024] = relu(bn1(xT @ w1^T))
  gemm_bf16<1, u16><<<dim3(8, 24, 4), blk, 0, stream>>>(
      GArgs<u16>{xTu, 1572864L, 512, w1b, 0L, 512, y1u, 3145728L, 1024,
                 3072, 1024, 512, s1f, f1f, 0.f, nullptr});
  // MLP2: feat[pos,512] + dual-write featT[512,3072]
  gemm_bf16<6, u16><<<dim3(4, 24, 4), blk, 0, stream>>>(
      GArgs<u16>{y1u, 3145728L, 1024, w2b, 0L, 1024, featu, 1572864L, 512,
                 3072, 512, 1024, s2f, f2f, 0.f, featTu});
  // phi[p,i] f32 + phiT[i,p] f32 in one pass
  gemm_bf16<5, float><<<dim3(8, 16, 4), blk, 0, stream>>>(
      GArgs<float>{featu, 1572864L, 512, featu + 1048576, 1572864L, 512, phi, 2097152L, 1024,
                   2048, 1024, 512, nullptr, nullptr, 0.044194173824159216f, phiT});
  softmax_k<4><<<dim3(2048, 4), blk, 0, stream>>>(phi, smI, 2097152L);    // softmax over i
  softmax_k<8><<<dim3(1024, 4), blk, 0, stream>>>(phiT, smPT, 2097152L);  // softmax over p
  // Xi[i,c] & Xp[p,c] merged
  gemm_pair<0, u16><<<dim3(4, 16, 8), blk, 0, stream>>>(
      GArgs<u16>{smPT, 2097152L, 2048, featTu, 1572864L, 3072, Xi, 524288L, 512,
                 1024, 512, 2048, nullptr, nullptr, 0.f, nullptr},
      GArgs<u16>{smI, 2097152L, 1024, featTu + 2048, 1572864L, 3072, Xp, 1048576L, 512,
                 2048, 512, 1024, nullptr, nullptr, 0.f, nullptr}, 8, 4);
  // QK projections att0+att1 merged
  gemm_pair<3, u16><<<dim3(8, 16, 8), blk, 0, stream>>>(
      GArgs<u16>{Xi, 524288L, 512, qkwb, 0L, 512, qk0, 1048576L, 1024,
                 1024, 1024, 512, nullptr, qkbf, 0.f, nullptr},
      GArgs<u16>{Xp, 1048576L, 512, qkwb + 524288, 0L, 512, qk1, 2097152L, 1024,
                 2048, 1024, 512, nullptr, qkbf + 1024, 0.f, nullptr}, 8, 8);
  // V projections (transposed output) att0+att1 merged
  gemm_pair<4, u16><<<dim3(16, 4, 8), blk, 0, stream>>>(
      GArgs<u16>{vwb, 0L, 512, Xi, 524288L, 512, vT0, 524288L, 1024,
                 512, 1024, 512, nullptr, vb, 0.f, nullptr},
      GArgs<u16>{vwb + 262144, 0L, 512, Xp, 1048576L, 512, vT1, 1048576L, 2048,
                 512, 2048, 512, nullptr, vb + 512, 0.f, nullptr}, 4, 8);
  // attention att0 (full) + att1 (2-way KV split) merged
  attn_flash_pair<<<dim3(16, 4, 12), dim3(512), 0, stream>>>(
      qk0, vT0, out0, qk1, vT1, P0a1, P1a1, ml1);
  // add+LN: att0 -> joint rows 2048..3071; att1 combine -> joint rows 0..2047
  add_ln_pair2<<<dim3(2048, 4, 2), blk, 0, stream>>>(
      out0, Xi, lng, lnb, jointu + 1048576, 1572864L,
      P0a1, P1a1, ml1, Xp, lng + 512, lnb + 512, jointu, 1572864L);
  // ---- att2: S=3072 on joint, 2-way KV split ----
  gemm_bf16<3, u16><<<dim3(8, 24, 4), blk, 0, stream>>>(
      GArgs<u16>{jointu, 1572864L, 512, qkwb + 1048576, 0L, 512, qkbu, 3145728L, 1024,
                 3072, 1024, 512, nullptr, qkbf + 2048, 0.f, nullptr});
  gemm_bf16<4, u16><<<dim3(24, 4, 4), blk, 0, stream>>>(
      GArgs<u16>{vwb + 524288, 0L, 512, jointu, 1572864L, 512, vTu, 1572864L, 3072,
                 512, 3072, 512, nullptr, vb + 1024, 0.f, nullptr});
  attn_flash_split<<<dim3(24, 4, 8), dim3(512), 0, stream>>>(qkbu, vTu, P0a2, P1a2, ml2, 3072);
  add_ln_comb<<<dim3(3072, 4), blk, 0, stream>>>(P0a2, P1a2, ml2, jointu,
      lng + 1024, lnb + 1024, out, 1572864L, 3072);
}